// Round 1
// baseline (103.235 us; speedup 1.0000x reference)
//
#include <hip/hip_runtime.h>

// RelationalDense: out[n,:] = feat[n,:] @ W[rel[n]] + bias,  W = einsum('rb,bfo', lin, V)
// N=65536, F=64, U=64, R=25, B=8.
//
// Strategy: bucket rows by relation so every wave is relation-uniform; then the
// per-row 16 KB W read becomes a wave-uniform scalar (SMEM) broadcast instead of
// a 23-cacheline gather (which would cost ~1 GB of L1/L2 traffic = 26+ us).
// Memory floor: 16 MB feat read + 16 MB out write ~= 5.1 us; fp32 VALU 0.54 GF
// ~= 3.4 us (no fp32 MFMA on CDNA4); overlapped -> memory-bound target.

#define NN 65536
#define FF 64
#define UU 64
#define RR 25
#define BB 8
#define CAP 4096                 // slots per relation bucket; mean fill 2621, +29 sigma safe
#define NSLOT (RR * CAP)         // 102400

// ws layout:
//   [0, NSLOT*4)           idx_sorted (int), memset 0xFF (-1 = empty slot)
//   [NSLOT*4, +128)        cursors (25 ints), memset 0
//   [W_OFF, +R*F*U*4)      W fp32
#define IDX_OFF 0
#define CUR_OFF (NSLOT * 4)
#define W_OFF   (NSLOT * 4 + 128)
#define WS_NEED ((size_t)(W_OFF + RR * FF * UU * 4))

// ---------------------------------------------------------------------------
// K1: fused W precompute (blocks [0,400)) + bucket scatter (blocks [400,656))
// ---------------------------------------------------------------------------
__global__ __launch_bounds__(256) void k_prep(
    const float* __restrict__ kern,   // [B,F,U]
    const float* __restrict__ lin,    // [R,B]
    const int*   __restrict__ rel,    // [N]
    float*       __restrict__ W,      // [R,F,U]
    int*         __restrict__ idx_sorted,
    int*         __restrict__ cursors) {
  const int wblocks = (RR * FF * UU) / 256;  // 400
  int bid = blockIdx.x;
  if (bid < wblocks) {
    // W[r, fo] = sum_b lin[r,b] * V[b, fo]; idx>>12 is wave-uniform (4096%64==0)
    int idx = bid * 256 + threadIdx.x;
    int r  = __builtin_amdgcn_readfirstlane(idx >> 12);
    int fo = idx & (FF * UU - 1);
    float acc = 0.f;
#pragma unroll
    for (int b = 0; b < BB; ++b)
      acc += lin[r * BB + b] * kern[b * (FF * UU) + fo];
    W[idx] = acc;
  } else {
    // scatter: block of 256 rows -> LDS histogram -> reserve global range -> place
    int sb  = bid - wblocks;
    int tid = threadIdx.x;
    __shared__ int cnt[RR], base[RR], lcur[RR];
    if (tid < RR) { cnt[tid] = 0; lcur[tid] = 0; }
    __syncthreads();
    int row = sb * 256 + tid;
    int r = rel[row];
    atomicAdd(&cnt[r], 1);
    __syncthreads();
    if (tid < RR) base[tid] = atomicAdd(&cursors[tid], cnt[tid]);
    __syncthreads();
    int loc = atomicAdd(&lcur[r], 1);
    idx_sorted[r * CAP + base[r] + loc] = row;
  }
}

// ---------------------------------------------------------------------------
// K2: main compute. thread = (slot, quarter q of 16 output cols).
// Block 256 = 64 slots x 4 quarters; wave = 64 consecutive slots, so r and q
// are wave-uniform -> W/bias loads scalarize to s_load (SMEM broadcast).
// ---------------------------------------------------------------------------
__global__ __launch_bounds__(256) void k_main(
    const float* __restrict__ features,  // [N,F]
    const float* __restrict__ bias,      // [U]
    const float* __restrict__ W,         // [R,F,U]
    const int*   __restrict__ idx_sorted,
    float*       __restrict__ out) {     // [N,U]
  int tid  = threadIdx.x;
  int slot = blockIdx.x * 64 + (tid & 63);
  int row  = idx_sorted[slot];
  if (row < 0) return;  // empty tail of a bucket
  int q = __builtin_amdgcn_readfirstlane(tid >> 6);    // 0..3, uniform per wave
  int r = __builtin_amdgcn_readfirstlane(slot >> 12);  // CAP=4096, uniform per wave

  const float*  Wq = W + r * (FF * UU) + q * 16;       // uniform -> SMEM
  const float4* fr = reinterpret_cast<const float4*>(features + (size_t)row * FF);

  float4 fv[16];
#pragma unroll
  for (int i = 0; i < 16; ++i) fv[i] = fr[i];          // per-lane row gather, 256B/row

  float acc[16];
#pragma unroll
  for (int j = 0; j < 16; ++j) acc[j] = bias[q * 16 + j];  // uniform -> SMEM

#pragma unroll
  for (int fc = 0; fc < 16; ++fc) {
#pragma unroll
    for (int c = 0; c < 4; ++c) {
      int f = fc * 4 + c;
      float fs = (c == 0) ? fv[fc].x : (c == 1) ? fv[fc].y : (c == 2) ? fv[fc].z : fv[fc].w;
#pragma unroll
      for (int j = 0; j < 16; ++j)
        acc[j] += fs * Wq[f * UU + j];                 // v_fmac with SGPR W operand
    }
  }

  float4* o4 = reinterpret_cast<float4*>(out + (size_t)row * UU + q * 16);
#pragma unroll
  for (int j4 = 0; j4 < 4; ++j4)
    o4[j4] = make_float4(acc[4 * j4], acc[4 * j4 + 1], acc[4 * j4 + 2], acc[4 * j4 + 3]);
}

// ---------------------------------------------------------------------------
// Fallback (no workspace needed): compute W_r columns on the fly per row.
// Only used if ws_size is unexpectedly small. Correct but ~30 us.
// ---------------------------------------------------------------------------
__global__ __launch_bounds__(256) void k_fallback(
    const float* __restrict__ features,
    const int*   __restrict__ rel,
    const float* __restrict__ kern,
    const float* __restrict__ lin,
    const float* __restrict__ bias,
    float*       __restrict__ out) {
  int tid = threadIdx.x;
  int row = blockIdx.x * 64 + (tid & 63);
  int q   = __builtin_amdgcn_readfirstlane(tid >> 6);
  int r   = rel[row];
  float cf[BB];
#pragma unroll
  for (int b = 0; b < BB; ++b) cf[b] = lin[r * BB + b];
  const float4* fr = reinterpret_cast<const float4*>(features + (size_t)row * FF);
  float4 fv[16];
#pragma unroll
  for (int i = 0; i < 16; ++i) fv[i] = fr[i];
  float acc[16];
#pragma unroll
  for (int j = 0; j < 16; ++j) acc[j] = bias[q * 16 + j];
#pragma unroll
  for (int fc = 0; fc < 16; ++fc) {
#pragma unroll
    for (int c = 0; c < 4; ++c) {
      int f = fc * 4 + c;
      float fs = (c == 0) ? fv[fc].x : (c == 1) ? fv[fc].y : (c == 2) ? fv[fc].z : fv[fc].w;
      float wf[16];
#pragma unroll
      for (int j = 0; j < 16; ++j) wf[j] = 0.f;
#pragma unroll
      for (int b = 0; b < BB; ++b) {
        const float* Vb = kern + b * (FF * UU) + f * UU + q * 16;  // uniform -> SMEM
#pragma unroll
        for (int j = 0; j < 16; ++j) wf[j] += cf[b] * Vb[j];
      }
#pragma unroll
      for (int j = 0; j < 16; ++j) acc[j] += fs * wf[j];
    }
  }
  float4* o4 = reinterpret_cast<float4*>(out + (size_t)row * UU + q * 16);
#pragma unroll
  for (int j4 = 0; j4 < 4; ++j4)
    o4[j4] = make_float4(acc[4 * j4], acc[4 * j4 + 1], acc[4 * j4 + 2], acc[4 * j4 + 3]);
}

extern "C" void kernel_launch(void* const* d_in, const int* in_sizes, int n_in,
                              void* d_out, int out_size, void* d_ws, size_t ws_size,
                              hipStream_t stream) {
  const float* features  = (const float*)d_in[0];
  const int*   relations = (const int*)d_in[1];
  const float* kern      = (const float*)d_in[2];
  const float* lin       = (const float*)d_in[3];
  const float* bias      = (const float*)d_in[4];
  float* out = (float*)d_out;

  if (ws_size >= WS_NEED) {
    char*  ws         = (char*)d_ws;
    int*   idx_sorted = (int*)(ws + IDX_OFF);
    int*   cursors    = (int*)(ws + CUR_OFF);
    float* W          = (float*)(ws + W_OFF);
    hipMemsetAsync(idx_sorted, 0xFF, NSLOT * sizeof(int), stream);
    hipMemsetAsync(cursors, 0, RR * sizeof(int), stream);
    k_prep<<<(RR * FF * UU) / 256 + NN / 256, 256, 0, stream>>>(
        kern, lin, relations, W, idx_sorted, cursors);
    k_main<<<NSLOT / 64, 256, 0, stream>>>(features, bias, W, idx_sorted, out);
  } else {
    k_fallback<<<NN / 64, 256, 0, stream>>>(features, relations, kern, lin, bias, out);
  }
}